// Round 4
// baseline (249.407 us; speedup 1.0000x reference)
//
#include <hip/hip_runtime.h>

#define NN 4096

// ---------------- Phase 1: partial column sums of yin @ (w + alpha*hebb) ----
// Grid (4, NN/RPB), block 256, 8 blocks/CU forced. Each thread owns 4
// consecutive columns (float4) and accumulates RPB rows, 2 rows (6 float4
// loads) in flight per batch. Writes one partial row per (rowblock, col).
template <int RPB>
__global__ __launch_bounds__(256, 8) void matvec_partial_kernel(
    const float* __restrict__ yin,
    const float* __restrict__ w,
    const float* __restrict__ alpha,
    const float* __restrict__ hebb,
    float* __restrict__ part)
{
    const int col = blockIdx.x * 1024 + threadIdx.x * 4;
    const int r0  = blockIdx.y * RPB;

    float4 acc = make_float4(0.f, 0.f, 0.f, 0.f);
    #pragma unroll
    for (int b = 0; b < RPB / 2; ++b) {
        const int i0 = r0 + 2 * b;
        const size_t off0 = (size_t)i0 * NN + col;
        const size_t off1 = off0 + NN;
        const float4 w0 = *reinterpret_cast<const float4*>(w + off0);
        const float4 a0 = *reinterpret_cast<const float4*>(alpha + off0);
        const float4 h0 = *reinterpret_cast<const float4*>(hebb + off0);
        const float4 w1 = *reinterpret_cast<const float4*>(w + off1);
        const float4 a1 = *reinterpret_cast<const float4*>(alpha + off1);
        const float4 h1 = *reinterpret_cast<const float4*>(hebb + off1);
        const float y0 = yin[i0];
        const float y1 = yin[i0 + 1];
        acc.x += y0 * (w0.x + a0.x * h0.x) + y1 * (w1.x + a1.x * h1.x);
        acc.y += y0 * (w0.y + a0.y * h0.y) + y1 * (w1.y + a1.y * h1.y);
        acc.z += y0 * (w0.z + a0.z * h0.z) + y1 * (w1.z + a1.z * h1.z);
        acc.w += y0 * (w0.w + a0.w * h0.w) + y1 * (w1.w + a1.w * h1.w);
    }
    *reinterpret_cast<float4*>(part + (size_t)blockIdx.y * NN + col) = acc;
}

// ---------------- Phase 2: reduce partial rows -> yout = tanh(sum + input) --
// Grid 64 x 256. Block handles 64 columns; 4 row-slices LDS-reduced.
__global__ __launch_bounds__(256) void reduce_yout_kernel(
    const float* __restrict__ part,
    const float* __restrict__ input,
    float* __restrict__ yout,
    int rows)
{
    const int tid   = threadIdx.x;
    const int j     = blockIdx.x * 64 + (tid & 63);
    const int slice = tid >> 6;           // 0..3
    const int per   = rows >> 2;

    float s = 0.f;
    #pragma unroll 8
    for (int kk = 0; kk < per; ++kk)
        s += part[(size_t)(slice * per + kk) * NN + j];

    __shared__ float sm[256];
    sm[tid] = s;
    __syncthreads();
    if (tid < 64) {
        float tot = sm[tid] + sm[tid + 64] + sm[tid + 128] + sm[tid + 192];
        yout[j] = tanhf(tot + input[j]);
    }
}

// ---------------- Phase 3: hebb' = (1-eta)*hebb + eta*outer(yin,yout) -------
// 2048 blocks x 256 threads x 8 float4 = exactly NN*NN floats.
// Two batches of 4 float4 in flight; stride multiple of row length keeps the
// yout column vector constant per thread.
__global__ __launch_bounds__(256, 8) void hebb_update_kernel(
    const float* __restrict__ hebb,
    const float* __restrict__ yin,
    const float* __restrict__ yout,
    const float* __restrict__ eta_p,
    float* __restrict__ hebb_out)
{
    const float eta = eta_p[0];
    const float om  = 1.0f - eta;
    const int tid   = blockIdx.x * 256 + threadIdx.x;   // 0..524287
    const int NT    = 2048 * 256;                       // stride in float4

    const float4 yo = reinterpret_cast<const float4*>(yout)[tid & 1023];

    #pragma unroll
    for (int half = 0; half < 2; ++half) {
        float4 hv[4];
        float  ye[4];
        #pragma unroll
        for (int it = 0; it < 4; ++it) {
            const int g = tid + (half * 4 + it) * NT;
            hv[it] = reinterpret_cast<const float4*>(hebb)[g];
            ye[it] = eta * yin[g >> 10];
        }
        #pragma unroll
        for (int it = 0; it < 4; ++it) {
            const int g = tid + (half * 4 + it) * NT;
            float4 r;
            r.x = om * hv[it].x + ye[it] * yo.x;
            r.y = om * hv[it].y + ye[it] * yo.y;
            r.z = om * hv[it].z + ye[it] * yo.z;
            r.w = om * hv[it].w + ye[it] * yo.w;
            reinterpret_cast<float4*>(hebb_out)[g] = r;
        }
    }
}

extern "C" void kernel_launch(void* const* d_in, const int* in_sizes, int n_in,
                              void* d_out, int out_size, void* d_ws, size_t ws_size,
                              hipStream_t stream) {
    const float* input = (const float*)d_in[0];
    const float* yin   = (const float*)d_in[1];
    const float* hebb  = (const float*)d_in[2];
    const float* w     = (const float*)d_in[3];
    const float* alpha = (const float*)d_in[4];
    const float* eta   = (const float*)d_in[5];

    float* out      = (float*)d_out;
    float* yout     = out;        // first NN elements
    float* hebb_out = out + NN;   // next NN*NN elements
    float* part     = (float*)d_ws;

    const size_t bytes_1024 = (size_t)1024 * NN * sizeof(float);  // 16 MiB

    if (ws_size >= bytes_1024) {
        // High-occupancy config: 4096 WGs, 4 rows each, 1024 partial rows.
        dim3 g1(4, 1024);
        matvec_partial_kernel<4><<<g1, 256, 0, stream>>>(yin, w, alpha, hebb, part);
        reduce_yout_kernel<<<NN / 64, 256, 0, stream>>>(part, input, yout, 1024);
    } else {
        // Proven 4 MiB fallback: 1024 WGs, 16 rows each, 256 partial rows.
        dim3 g1(4, 256);
        matvec_partial_kernel<16><<<g1, 256, 0, stream>>>(yin, w, alpha, hebb, part);
        reduce_yout_kernel<<<NN / 64, 256, 0, stream>>>(part, input, yout, 256);
    }

    hebb_update_kernel<<<2048, 256, 0, stream>>>(hebb, yin, yout, eta, hebb_out);
}